// Round 11
// baseline (679.256 us; speedup 1.0000x reference)
//
#include <hip/hip_runtime.h>
#include <hip/hip_bf16.h>
#include <math.h>

#define NNODES 50000
#define NEDGES 800000
#define NROWS  9
#define TOTROWS (NNODES * NROWS)   // 450000
#define MKBLK  7032                // ceil(450000/64)

typedef _Float16 f16;
typedef _Float16 f16x8 __attribute__((ext_vector_type(8)));
typedef _Float16 f16x4 __attribute__((ext_vector_type(4)));
typedef float    f32x4 __attribute__((ext_vector_type(4)));

__device__ __forceinline__ float silu(float x) { return x / (1.0f + __expf(-x)); }

__device__ __forceinline__ f16x8 zero8() {
    f16x8 v;
    #pragma unroll
    for (int i = 0; i < 8; ++i) v[i] = (f16)0.0f;
    return v;
}

// ---------------------------------------------------------------------------
// front_k: fused wprep (blocks [0,1536)) + prep ([1536,7786)) + hist (rest).
// ---------------------------------------------------------------------------
__global__ __launch_bounds__(256) void front_k(
    const float* __restrict__ W1, const float* __restrict__ W2,
    const float* __restrict__ Wg1, const float* __restrict__ Wg2,
    f16* __restrict__ W1T, f16* __restrict__ W2T,
    f16* __restrict__ Wg1T, f16* __restrict__ Wg2T,
    const float* __restrict__ x, f16* __restrict__ base, f16* __restrict__ norms,
    const int* __restrict__ dst, int* __restrict__ cnt)
{
    const int b = blockIdx.x;
    const int t = threadIdx.x;
    if (b < 1536) {
        // ---- weight transpose + f16 convert; dest [out_col][k] ----
        int i = b * 256 + t;
        if (i < 32768) {  // W1T[n=256][k=128]
            int n = i >> 7, k = i & 127;
            W1T[i] = (f16)W1[k * 256 + n];
        }
        if (i < 32768) {  // W2T[s=128][k=256]
            int s = i >> 8, k = i & 255;
            W2T[i] = (f16)W2[k * 128 + s];
        }
        if (i < 393216) { // Wg1T[l][h=256][k=512]
            int l = i >> 17, r = i & 131071;
            int h = r >> 9, k = r & 511;
            Wg1T[i] = (f16)Wg1[l * 131072 + k * 256 + h];
        }
        if (i < 196608) { // Wg2T[l][h=256][k=256]
            int l = i >> 16, r = i & 65535;
            int h = r >> 8, k = r & 255;
            Wg2T[i] = (f16)Wg2[l * 65536 + k * 256 + h];
        }
    } else if (b < 1536 + 6250) {
        // ---- per-node prep: x0 slot of base + norms (NT reads, read-once) ----
        int node = (b - 1536) * 8 + (t >> 5);
        int c4 = (t & 31) * 4;
        const float* xr = x + (size_t)node * (NROWS * 128) + c4;
        f32x4 v0 = __builtin_nontemporal_load((const f32x4*)xr);
        f32x4 s1 = {0,0,0,0}, s2 = {0,0,0,0};
        #pragma unroll
        for (int r = 1; r < 4; ++r) {
            f32x4 v = __builtin_nontemporal_load((const f32x4*)(xr + r * 128));
            s1 += v * v;
        }
        #pragma unroll
        for (int r = 4; r < 9; ++r) {
            f32x4 v = __builtin_nontemporal_load((const f32x4*)(xr + r * 128));
            s2 += v * v;
        }
        f16x4 b0, n0v, n1v, n2v;
        #pragma unroll
        for (int i = 0; i < 4; ++i) {
            b0[i]  = (f16)v0[i];
            n0v[i] = (f16)fabsf(v0[i]);
            n1v[i] = (f16)sqrtf(s1[i]);
            n2v[i] = (f16)sqrtf(s2[i]);
        }
        *(f16x4*)(base + (size_t)node * 384 + 256 + c4) = b0;
        *(f16x4*)(norms + (size_t)node * 128 + c4) = n0v;
        *(f16x4*)(norms + ((size_t)NNODES + node) * 128 + c4) = n1v;
        *(f16x4*)(norms + ((size_t)2 * NNODES + node) * 128 + c4) = n2v;
    } else {
        // ---- histogram ----
        int e = (b - 1536 - 6250) * 256 + t;
        if (e < NEDGES) atomicAdd(&cnt[dst[e]], 1);
    }
}

// ---------------------------------------------------------------------------
// CSR scan + fill
// ---------------------------------------------------------------------------
__global__ __launch_bounds__(1024) void scan_k(const int* __restrict__ cnt, int* __restrict__ row_start)
{
    __shared__ int part[1024];
    int t = threadIdx.x;
    int lo = t * 49, hi = min(lo + 49, NNODES);
    int s = 0;
    for (int i = lo; i < hi; ++i) s += cnt[i];
    part[t] = s;
    __syncthreads();
    for (int off = 1; off < 1024; off <<= 1) {
        int v = (t >= off) ? part[t - off] : 0;
        __syncthreads();
        part[t] += v;
        __syncthreads();
    }
    int run = part[t] - s;
    for (int i = lo; i < hi; ++i) { row_start[i] = run; run += cnt[i]; }
}

__global__ __launch_bounds__(256) void fill_k(
    const int* __restrict__ dst, const int* __restrict__ row_start,
    int* __restrict__ cur, int* __restrict__ eids)
{
    int e = blockIdx.x * 256 + threadIdx.x;
    if (e >= NEDGES) return;
    int d = dst[e];
    int p = atomicAdd(&cur[d], 1);
    eids[row_start[d] + p] = e;
}

// ---------------------------------------------------------------------------
// Gather means: wave per node. Coalesced eids load (64/chunk) + shfl
// broadcast with WAVE-UNIFORM control flow; unroll 4 -> up to 16 edges in
// flight; launch_bounds(256,4) caps VGPR<=128 so occupancy stays 16 waves/CU.
// ---------------------------------------------------------------------------
__global__ __launch_bounds__(256, 4) void gather_k(
    const float* __restrict__ t_ij, const float* __restrict__ a_ij,
    const int* __restrict__ row_start, const int* __restrict__ cnt,
    const int* __restrict__ eids, f16* __restrict__ base)
{
    int wv = threadIdx.x >> 6, ln = threadIdx.x & 63;
    int node = blockIdx.x * 4 + wv;
    int rs = row_start[node];
    int n  = cnt[node];
    int qw = ln >> 4, q = ln & 15;
    f32x4 tc0 = {0,0,0,0}, tc1 = {0,0,0,0}, ac0 = {0,0,0,0}, ac1 = {0,0,0,0};
    for (int b0 = 0; b0 < n; b0 += 64) {          // wave-uniform bound
        int ecnt = min(64, n - b0);
        int eid = (b0 + ln < n) ? eids[rs + b0 + ln] : 0;
        #pragma unroll 4
        for (int i0 = 0; i0 < ecnt; i0 += 4) {    // wave-uniform bound
            int i = i0 + qw;                       // this lane's edge in group
            int e = __shfl(eid, i & 63);           // all 64 lanes execute
            if (i < ecnt) {
                const f32x4* tr = (const f32x4*)(t_ij + (size_t)e * 128 + q * 8);
                const f32x4* ar = (const f32x4*)(a_ij + (size_t)e * 128 + q * 8);
                f32x4 t0 = __builtin_nontemporal_load(tr);
                f32x4 t1 = __builtin_nontemporal_load(tr + 1);
                f32x4 a0 = __builtin_nontemporal_load(ar);
                f32x4 a1 = __builtin_nontemporal_load(ar + 1);
                tc0 += t0; tc1 += t1; ac0 += a0; ac1 += a1;
            }
        }
    }
    #pragma unroll
    for (int m = 16; m <= 32; m <<= 1) {
        #pragma unroll
        for (int i = 0; i < 4; ++i) {
            tc0[i] += __shfl_xor(tc0[i], m);
            tc1[i] += __shfl_xor(tc1[i], m);
            ac0[i] += __shfl_xor(ac0[i], m);
            ac1[i] += __shfl_xor(ac1[i], m);
        }
    }
    float inv = 1.0f / (float)(n > 0 ? n : 1);
    if (qw == 0) {          // c_i channels q*8..q*8+7
        f16x8 v;
        #pragma unroll
        for (int i = 0; i < 4; ++i) {
            v[i]     = (f16)(tc0[i] * inv);
            v[4 + i] = (f16)(tc1[i] * inv);
        }
        *(f16x8*)(base + (size_t)node * 384 + q * 8) = v;
    } else if (qw == 1) {   // c_ang
        f16x8 v;
        #pragma unroll
        for (int i = 0; i < 4; ++i) {
            v[i]     = (f16)(ac0[i] * inv);
            v[4 + i] = (f16)(ac1[i] * inv);
        }
        *(f16x8*)(base + (size_t)node * 384 + 128 + q * 8) = v;
    }
}

// ---------------------------------------------------------------------------
// Gate MLP, one l per blockIdx.y. 64 nodes/block, 256 threads (4 waves).
// B streamed through 20KB padded LDS (k=32 slabs); g1 in 32KB swizzled LDS.
// 52KB LDS -> 3 blocks/CU (12 waves).
// ---------------------------------------------------------------------------
__global__ __launch_bounds__(256, 3) void gate_k(
    const f16* __restrict__ base, const f16* __restrict__ norms,
    const f16* __restrict__ Wg1T, const f16* __restrict__ Wg2T,
    const float* __restrict__ bg1, const float* __restrict__ bg2,
    f16* __restrict__ g2out)
{
    const int l  = blockIdx.y;
    const int n0 = blockIdx.x * 64;
    const int t  = threadIdx.x;
    const int wv = t >> 6, ln = t & 63;
    const int col0 = ln & 15, kq = ln >> 4;

    __shared__ f16 bs[256][40];      // [n=256][k=32] pad->40 (2-way max), 20KB
    __shared__ f16 g1l[64 * 256];    // swizzled, 32KB

    const int anode = n0 + wv * 16 + col0;
    const bool aok = anode < NNODES;

    f32x4 acc[16];
    #pragma unroll
    for (int nt = 0; nt < 16; ++nt) {
        float b = bg1[l * 256 + nt * 16 + col0];
        f32x4 v = {b, b, b, b};
        acc[nt] = v;
    }

    const f16* wg1 = Wg1T + (size_t)l * 131072;
    #pragma unroll
    for (int slab = 0; slab < 16; ++slab) {
        #pragma unroll
        for (int it = 0; it < 4; ++it) {
            int idx = t + 256 * it;
            int row = idx >> 2, g = idx & 3;
            *(f16x8*)&bs[row][g * 8] =
                *(const f16x8*)(wg1 + (size_t)row * 512 + slab * 32 + g * 8);
        }
        __syncthreads();
        const f16* asrc;
        if (slab < 8)       asrc = base  + (size_t)anode * 384 + slab * 32;
        else if (slab < 12) asrc = norms + ((size_t)l * NNODES + anode) * 128 + (slab - 8) * 32;
        else                asrc = base  + (size_t)anode * 384 + 256 + (slab - 12) * 32;
        f16x8 a = zero8();
        if (aok) a = *(const f16x8*)(asrc + kq * 8);
        #pragma unroll
        for (int nt = 0; nt < 16; ++nt) {
            f16x8 b = *(const f16x8*)&bs[nt * 16 + col0][kq * 8];
            acc[nt] = __builtin_amdgcn_mfma_f32_16x16x32_f16(a, b, acc[nt], 0, 0, 0);
        }
        __syncthreads();
    }

    // g1 = silu(acc) -> swizzled LDS (wave-local rows)
    #pragma unroll
    for (int nt = 0; nt < 16; ++nt)
        #pragma unroll
        for (int j = 0; j < 4; ++j) {
            int row = wv * 16 + kq * 4 + j;
            int col = nt * 16 + col0;
            int g = (col >> 3) ^ (row & 7);
            g1l[row * 256 + g * 8 + (col & 7)] = (f16)silu(acc[nt][j]);
        }

    f32x4 acc2[16];
    #pragma unroll
    for (int nt = 0; nt < 16; ++nt) {
        float b = bg2[l * 256 + nt * 16 + col0];
        f32x4 v = {b, b, b, b};
        acc2[nt] = v;
    }
    const f16* wg2 = Wg2T + (size_t)l * 65536;
    #pragma unroll
    for (int slab = 0; slab < 8; ++slab) {
        #pragma unroll
        for (int it = 0; it < 4; ++it) {
            int idx = t + 256 * it;
            int row = idx >> 2, g = idx & 3;
            *(f16x8*)&bs[row][g * 8] =
                *(const f16x8*)(wg2 + (size_t)row * 256 + slab * 32 + g * 8);
        }
        __syncthreads();
        int arow = wv * 16 + col0;
        int gk = slab * 4 + kq;                     // global k-granule 0..31
        f16x8 a = *(const f16x8*)&g1l[arow * 256 + (gk ^ (arow & 7)) * 8];
        #pragma unroll
        for (int nt = 0; nt < 16; ++nt) {
            f16x8 b = *(const f16x8*)&bs[nt * 16 + col0][kq * 8];
            acc2[nt] = __builtin_amdgcn_mfma_f32_16x16x32_f16(a, b, acc2[nt], 0, 0, 0);
        }
        __syncthreads();
    }

    // g2 = silu(acc2) -> g1l (reuse), then coalesced swizzle-aware copy out
    #pragma unroll
    for (int nt = 0; nt < 16; ++nt)
        #pragma unroll
        for (int j = 0; j < 4; ++j) {
            int row = wv * 16 + kq * 4 + j;
            int col = nt * 16 + col0;
            int g = (col >> 3) ^ (row & 7);
            g1l[row * 256 + g * 8 + (col & 7)] = (f16)silu(acc2[nt][j]);
        }
    __syncthreads();
    #pragma unroll
    for (int it = 0; it < 8; ++it) {
        int idx = t + 256 * it;          // 2048 granules
        int row = idx >> 5, g = idx & 31;
        int node = n0 + row;
        if (node < NNODES) {
            f16x8 v = *(const f16x8*)&g1l[row * 256 + (g ^ (row & 7)) * 8];
            *(f16x8*)(g2out + ((size_t)l * NNODES + node) * 256 + g * 8) = v;
        }
    }
}

// ---------------------------------------------------------------------------
// mk: fused h = x@W1 -> (silu l0) -> swizzled LDS; out = (h.*g)@W2.
// 64 rows/block, 256 threads, 3 blocks/CU. Slab-0 staging issued BEFORE the
// register prefetches so the first barrier clears sooner.
// ---------------------------------------------------------------------------
__global__ __launch_bounds__(256, 3) void mk_k(
    const float* __restrict__ x, const f16* __restrict__ g2,
    const f16* __restrict__ W1T, const f16* __restrict__ W2T,
    float* __restrict__ out)
{
    const int t  = threadIdx.x;
    const int wv = t >> 6, ln = t & 63;
    const int col0 = ln & 15, kq = ln >> 4;
    const int r0 = blockIdx.x * 64;

    __shared__ f16 bs[256][40];      // W slab [rows][k=32] pad->40, 20KB
    __shared__ f16 hl[64 * 256];     // h tile, swizzled, 32.75KB

    // ---- stage W1 slab 0 FIRST (barrier waits only on these) ----
    #pragma unroll
    for (int it = 0; it < 4; ++it) {
        int idx = t + 256 * it;
        int row = idx >> 2, g = idx & 3;
        *(f16x8*)&bs[row][g * 8] =
            *(const f16x8*)(W1T + (size_t)row * 128 + 0 * 32 + g * 8);
    }

    const int arow = r0 + wv * 16 + col0;
    const bool aok = arow < TOTROWS;
    const int ar  = aok ? arow : 0;
    const int node = ar / 9;
    const int p    = ar - node * 9;
    const int lsel = (p > 0) + (p > 3);
    const float* asrc = x + (size_t)ar * 128;
    const f16* grow = g2 + ((size_t)lsel * NNODES + node) * 256;

    // ---- prefetch A row (x, f32->f16, NT) and gate row into regs ----
    f16x8 ax[4];
    #pragma unroll
    for (int ks = 0; ks < 4; ++ks) {
        ax[ks] = zero8();
        if (aok) {
            f32x4 f0 = __builtin_nontemporal_load((const f32x4*)(asrc + ks * 32 + kq * 8));
            f32x4 f1 = __builtin_nontemporal_load((const f32x4*)(asrc + ks * 32 + kq * 8 + 4));
            #pragma unroll
            for (int i = 0; i < 4; ++i) {
                ax[ks][i]     = (f16)f0[i];
                ax[ks][4 + i] = (f16)f1[i];
            }
        }
    }
    f16x8 gpre[8];
    #pragma unroll
    for (int ks = 0; ks < 8; ++ks) {
        gpre[ks] = zero8();
        if (aok) gpre[ks] = *(const f16x8*)(grow + ks * 32 + kq * 8);
    }

    // ---- GEMM1: h = x @ W1, W1 in k=32 slabs (4), single-buffered ----
    f32x4 acc[16];
    #pragma unroll
    for (int nt = 0; nt < 16; ++nt) { f32x4 z = {0,0,0,0}; acc[nt] = z; }
    #pragma unroll
    for (int s = 0; s < 4; ++s) {
        if (s > 0) {
            #pragma unroll
            for (int it = 0; it < 4; ++it) {   // 1024 granules: 256 rows x 4
                int idx = t + 256 * it;
                int row = idx >> 2, g = idx & 3;
                *(f16x8*)&bs[row][g * 8] =
                    *(const f16x8*)(W1T + (size_t)row * 128 + s * 32 + g * 8);
            }
        }
        __syncthreads();
        #pragma unroll
        for (int nt = 0; nt < 16; ++nt) {
            f16x8 b = *(const f16x8*)&bs[nt * 16 + col0][kq * 8];
            acc[nt] = __builtin_amdgcn_mfma_f32_16x16x32_f16(ax[s], b, acc[nt], 0, 0, 0);
        }
        __syncthreads();
    }

    // ---- h (silu on l=0 rows) -> hl swizzled (wave-local rows) ----
    #pragma unroll
    for (int j = 0; j < 4; ++j) {
        int rl = wv * 16 + kq * 4 + j;
        int pj = (r0 + rl) % 9;
        if (pj == 0) {
            #pragma unroll
            for (int nt = 0; nt < 16; ++nt) {
                int col = nt * 16 + col0;
                int g = (col >> 3) ^ (rl & 7);
                hl[rl * 256 + g * 8 + (col & 7)] = (f16)silu(acc[nt][j]);
            }
        } else {
            #pragma unroll
            for (int nt = 0; nt < 16; ++nt) {
                int col = nt * 16 + col0;
                int g = (col >> 3) ^ (rl & 7);
                hl[rl * 256 + g * 8 + (col & 7)] = (f16)acc[nt][j];
            }
        }
    }
    // no barrier: GEMM2's A-rows (wv*16+col0) are wave-local; lgkmcnt orders

    // ---- GEMM2: out = (h .* g) @ W2, W2 in k=32 slabs (8), single-buf ----
    f32x4 acc2[8];
    #pragma unroll
    for (int nt = 0; nt < 8; ++nt) { f32x4 z = {0,0,0,0}; acc2[nt] = z; }
    const int arow2 = wv * 16 + col0;
    #pragma unroll
    for (int s = 0; s < 8; ++s) {
        #pragma unroll
        for (int it = 0; it < 2; ++it) {   // 512 granules: 128 rows x 4
            int idx = t + 256 * it;
            int row = idx >> 2, g = idx & 3;
            *(f16x8*)&bs[row][g * 8] =
                *(const f16x8*)(W2T + (size_t)row * 256 + s * 32 + g * 8);
        }
        __syncthreads();
        int gk = s * 4 + kq;
        f16x8 h8 = *(const f16x8*)&hl[arow2 * 256 + (gk ^ (arow2 & 7)) * 8];
        f16x8 a;
        #pragma unroll
        for (int i = 0; i < 8; ++i)
            a[i] = (f16)((float)h8[i] * (float)gpre[s][i]);
        #pragma unroll
        for (int nt = 0; nt < 8; ++nt) {
            f16x8 b = *(const f16x8*)&bs[nt * 16 + col0][kq * 8];
            acc2[nt] = __builtin_amdgcn_mfma_f32_16x16x32_f16(a, b, acc2[nt], 0, 0, 0);
        }
        __syncthreads();
    }
    #pragma unroll
    for (int j = 0; j < 4; ++j) {
        int gr = r0 + wv * 16 + kq * 4 + j;
        if (gr < TOTROWS) {
            #pragma unroll
            for (int nt = 0; nt < 8; ++nt)
                __builtin_nontemporal_store(acc2[nt][j],
                    out + (size_t)gr * 128 + nt * 16 + col0);
        }
    }
}

// ---------------------------------------------------------------------------
extern "C" void kernel_launch(void* const* d_in, const int* in_sizes, int n_in,
                              void* d_out, int out_size, void* d_ws, size_t ws_size,
                              hipStream_t stream) {
    const float* x_emb = (const float*)d_in[0];
    const float* t_ij  = (const float*)d_in[1];
    const float* a_ij  = (const float*)d_in[2];
    const int*   eidx  = (const int*)d_in[3];
    const float* W1  = (const float*)d_in[4];
    const float* W2  = (const float*)d_in[5];
    const float* Wg1 = (const float*)d_in[6];
    const float* bg1 = (const float*)d_in[7];
    const float* Wg2 = (const float*)d_in[8];
    const float* bg2 = (const float*)d_in[9];
    float* out = (float*)d_out;
    const int* dst = eidx + NEDGES;

    char* p = (char*)d_ws;
    int* cnt       = (int*)p;                 p += (size_t)NNODES * 4;
    int* cur       = (int*)p;                 p += (size_t)NNODES * 4;
    int* row_start = (int*)p;                 p += (size_t)(NNODES + 16) * 4;
    int* eids      = (int*)p;                 p += (size_t)NEDGES * 4;
    f16* base      = (f16*)p;                 p += (size_t)NNODES * 384 * 2;
    f16* norms     = (f16*)p;                 p += (size_t)3 * NNODES * 128 * 2;
    f16* g2b       = (f16*)p;                 p += (size_t)3 * NNODES * 256 * 2;
    f16* W1T       = (f16*)p;                 p += (size_t)32768 * 2;
    f16* W2T       = (f16*)p;                 p += (size_t)32768 * 2;
    f16* Wg1T      = (f16*)p;                 p += (size_t)393216 * 2;
    f16* Wg2T      = (f16*)p;                 p += (size_t)196608 * 2;

    hipMemsetAsync(cnt, 0, (size_t)2 * NNODES * 4, stream);  // cnt + cur

    front_k<<<1536 + 6250 + 3125, 256, 0, stream>>>(
        W1, W2, Wg1, Wg2, W1T, W2T, Wg1T, Wg2T, x_emb, base, norms, dst, cnt);
    scan_k<<<1, 1024, 0, stream>>>(cnt, row_start);
    fill_k<<<NEDGES / 256, 256, 0, stream>>>(dst, row_start, cur, eids);
    gather_k<<<NNODES / 4, 256, 0, stream>>>(t_ij, a_ij, row_start, cnt, eids, base);
    dim3 gg((NNODES + 63) / 64, 3);
    gate_k<<<gg, 256, 0, stream>>>(base, norms, Wg1T, Wg2T, bg1, bg2, g2b);
    mk_k<<<MKBLK, 256, 0, stream>>>(x_emb, g2b, W1T, W2T, out);
}